// Round 2
// baseline (2030.919 us; speedup 1.0000x reference)
//
#include <hip/hip_runtime.h>
#include <hip/hip_bf16.h>

// ---- problem constants ----
#define B_     4
#define N_     8192
#define MD_    512
#define OC_    536        // HEADS*(FEAT+3)
#define HEADS_ 8
#define FEAT_  64
#define NC_    32768      // 32^3 cells
#define ZTOT_  67108864ll // B*HEADS*FEAT*NC
#define NPTS_  262144     // B*HEADS*N
#define NCHUNK_ 16384     // 32 bh * 512 chunks of 64 cells
#define NENT_  2097152    // NPTS*8
#define NKEYS_ 786432.0f  // B*HEADS*3*N

// ============================================================
// Kernel 1: GEMM  kv[b][o][n] = sum_m W[o][m] * X[b][m][n]
// ============================================================
__global__ __launch_bounds__(256) void gemm_kernel(const float* __restrict__ W,
                                                   const float* __restrict__ X,
                                                   float* __restrict__ KV) {
  const int n0 = blockIdx.x * 256;
  const int m0 = blockIdx.y * 64;
  const int b  = blockIdx.z;
  __shared__ float Wt[32][68];    // Wt[k][m]
  __shared__ float In[32][260];   // In[k][n]
  const int t  = threadIdx.x;
  const int tx = t & 31;
  const int ty = t >> 5;
  float acc[8][8];
#pragma unroll
  for (int r = 0; r < 8; ++r)
#pragma unroll
    for (int c = 0; c < 8; ++c) acc[r][c] = 0.f;

  const float* Xb = X + (size_t)b * MD_ * N_;
  for (int k0 = 0; k0 < MD_; k0 += 32) {
#pragma unroll
    for (int i = 0; i < 8; ++i) {
      int idx = t + i * 256;
      int m = idx >> 5, k = idx & 31;
      int mm = m0 + m;
      Wt[k][m] = (mm < OC_) ? W[(size_t)mm * MD_ + (k0 + k)] : 0.f;
    }
#pragma unroll
    for (int i = 0; i < 8; ++i) {
      int slot = t + i * 256;
      int k = slot >> 6, n4 = slot & 63;
      float4 v = *(const float4*)(Xb + (size_t)(k0 + k) * N_ + n0 + n4 * 4);
      *(float4*)&In[k][n4 * 4] = v;
    }
    __syncthreads();
#pragma unroll
    for (int k = 0; k < 32; ++k) {
      float a[8], bb[8];
      *(float4*)&a[0]  = *(const float4*)&Wt[k][ty * 8];
      *(float4*)&a[4]  = *(const float4*)&Wt[k][ty * 8 + 4];
      *(float4*)&bb[0] = *(const float4*)&In[k][tx * 4];
      *(float4*)&bb[4] = *(const float4*)&In[k][128 + tx * 4];
#pragma unroll
      for (int r = 0; r < 8; ++r)
#pragma unroll
        for (int c = 0; c < 8; ++c)
          acc[r][c] = fmaf(a[r], bb[c], acc[r][c]);
    }
    __syncthreads();
  }
#pragma unroll
  for (int r = 0; r < 8; ++r) {
    int mm = m0 + ty * 8 + r;
    if (mm < OC_) {
      float* dst = KV + ((size_t)b * OC_ + mm) * N_ + n0;
      *(float4*)(dst + tx * 4)       = *(float4*)&acc[r][0];
      *(float4*)(dst + 128 + tx * 4) = *(float4*)&acc[r][4];
    }
  }
}

// ============================================================
// Kernel 2: BN stats per channel -> scale/shift
// ============================================================
__global__ __launch_bounds__(256) void bn_kernel(const float* __restrict__ KV,
                                                 const float* __restrict__ kg,
                                                 const float* __restrict__ kb,
                                                 const float* __restrict__ vg,
                                                 const float* __restrict__ vb,
                                                 float* __restrict__ scale,
                                                 float* __restrict__ shift) {
  const int o = blockIdx.x;
  const int t = threadIdx.x;
  float s = 0.f, s2 = 0.f;
  for (int idx = t; idx < B_ * N_; idx += 256) {
    int bb = idx >> 13, n = idx & (N_ - 1);
    float v = KV[((size_t)bb * OC_ + o) * N_ + n];
    s += v; s2 += v * v;
  }
#pragma unroll
  for (int off = 32; off; off >>= 1) {
    s  += __shfl_down(s, off);
    s2 += __shfl_down(s2, off);
  }
  __shared__ float rs[4], rs2[4];
  if ((t & 63) == 0) { rs[t >> 6] = s; rs2[t >> 6] = s2; }
  __syncthreads();
  if (t == 0) {
    s  = rs[0] + rs[1] + rs[2] + rs[3];
    s2 = rs2[0] + rs2[1] + rs2[2] + rs2[3];
    const float inv = 1.0f / (B_ * N_);
    float mu  = s * inv;
    float var = s2 * inv - mu * mu;
    float g, be;
    if (o < 24) { g = kg[o]; be = kb[o]; }
    else        { g = vg[o - 24]; be = vb[o - 24]; }
    float sc = g * rsqrtf(var + 1e-5f);
    scale[o] = sc;
    shift[o] = be - mu * sc;
  }
}

// ============================================================
// Kernel 3: BN-apply + transpose values -> vals[bh][n][f]
// ============================================================
__global__ __launch_bounds__(256) void valst_kernel(const float* __restrict__ KV,
                                                    const float* __restrict__ scale,
                                                    const float* __restrict__ shift,
                                                    float* __restrict__ vals) {
  const int bh = blockIdx.x >> 7;
  const int n0 = (blockIdx.x & 127) << 6;
  const int b = bh >> 3, h = bh & 7;
  __shared__ float T[64][65];
  const int t = threadIdx.x;
  const int ch0 = 24 + h * 64;
  const float* KVb = KV + (size_t)b * OC_ * N_;
#pragma unroll
  for (int i = 0; i < 16; ++i) {
    int idx = t + i * 256;
    int f = idx >> 6, p = idx & 63;
    int ch = ch0 + f;
    T[f][p] = fmaf(KVb[(size_t)ch * N_ + n0 + p], scale[ch], shift[ch]);
  }
  __syncthreads();
  float* dst = vals + ((size_t)bh * N_ + n0) * 64;
#pragma unroll
  for (int i = 0; i < 16; ++i) {
    int idx = t + i * 256;
    int p = idx >> 6, f = idx & 63;
    dst[(size_t)p * 64 + f] = T[f][p];
  }
}

// ============================================================
// Kernel 4: per-point keys -> cell + residuals; chunk histogram;
//           keys mean/var partials
// ============================================================
__global__ __launch_bounds__(256) void passk_kernel(const float* __restrict__ KV,
                                                    const float* __restrict__ orig,
                                                    const float* __restrict__ proj,
                                                    const float* __restrict__ scale,
                                                    const float* __restrict__ shift,
                                                    float4* __restrict__ cellr,
                                                    int* __restrict__ hist,
                                                    float* __restrict__ kacc) {
  const int p = blockIdx.x * 256 + threadIdx.x;
  const int bh = p >> 13, n = p & (N_ - 1);
  const int b = bh >> 3, h = bh & 7;
  const float* KVb = KV + (size_t)b * OC_ * N_;
  float pt[3];
#pragma unroll
  for (int k = 0; k < 3; ++k) {
    int ch = h * 3 + k;
    float kr = fmaf(KVb[(size_t)ch * N_ + n], scale[ch], shift[ch]);
    pt[k] = orig[((size_t)b * 3 + k) * N_ + n] + kr;
  }
  float ksum = 0.f, ksq = 0.f;
  int cell = 0;
  float rr[3];
#pragma unroll
  for (int d = 0; d < 3; ++d) {
    const float* pr = proj + (h * 3 + d) * 3;
    float key = pr[0] * pt[0] + pr[1] * pt[1] + pr[2] * pt[2];
    ksum += key; ksq += key * key;
    float lat = tanhf(key);
    float c = (lat + 1.0f) * 15.5f;
    float fl = floorf(c);
    fl = fminf(fmaxf(fl, 0.0f), 30.0f);
    rr[d] = c - fl;
    cell += (int)fl * ((d == 0) ? 1024 : (d == 1) ? 32 : 1);
  }
  cellr[p] = make_float4(rr[0], rr[1], rr[2], __int_as_float(cell));

  const int chunkbase = bh << 9;
#pragma unroll
  for (int c = 0; c < 8; ++c) {
    int cc = cell + ((c & 4) ? 1024 : 0) + ((c & 2) ? 32 : 0) + (c & 1);
    atomicAdd(&hist[chunkbase + (cc >> 6)], 1);
  }
#pragma unroll
  for (int off = 32; off; off >>= 1) {
    ksum += __shfl_down(ksum, off);
    ksq  += __shfl_down(ksq, off);
  }
  const int t = threadIdx.x;
  if ((t & 63) == 0) {
    atomicAdd(&kacc[0], ksum);
    atomicAdd(&kacc[1], ksq);
  }
}

// ============================================================
// Kernel 5: exclusive scan of 16384 chunk counts (single block)
// ============================================================
__global__ __launch_bounds__(256) void scan_kernel(int* __restrict__ hist) {
  __shared__ int sh[NCHUNK_];
  __shared__ int ts[256];
  const int t = threadIdx.x;
  for (int i = t; i < NCHUNK_; i += 256) sh[i] = hist[i];
  __syncthreads();
  const int base = t * 64;
  int s = 0;
  for (int j = 0; j < 64; ++j) s += sh[base + j];
  ts[t] = s;
  __syncthreads();
  if (t == 0) {
    int run = 0;
    for (int i = 0; i < 256; ++i) { int v = ts[i]; ts[i] = run; run += v; }
  }
  __syncthreads();
  int run = ts[t];
  for (int j = 0; j < 64; ++j) { int v = sh[base + j]; sh[base + j] = run; run += v; }
  __syncthreads();
  for (int i = t; i < NCHUNK_; i += 256) hist[i] = sh[i];
  if (t == 0) hist[NCHUNK_] = NENT_;
}

// ============================================================
// Kernel 6: scatter entries {weight, (cell&63)<<16 | n} into
//           chunk-sorted order
// ============================================================
__global__ __launch_bounds__(256) void scatter_kernel(const float4* __restrict__ cellr,
                                                      const int* __restrict__ binstart,
                                                      int* __restrict__ fill,
                                                      uint2* __restrict__ entries) {
  const int p = blockIdx.x * 256 + threadIdx.x;
  const int bh = p >> 13, n = p & (N_ - 1);
  float4 cr = cellr[p];
  const int cell = __float_as_int(cr.w);
  const float r0 = cr.x, r1 = cr.y, r2 = cr.z;
  const float u0 = 1.f - r0, u1 = 1.f - r1, u2 = 1.f - r2;
  const int chunkbase = bh << 9;
#pragma unroll
  for (int c = 0; c < 8; ++c) {
    float w = ((c & 4) ? r0 : u0) * ((c & 2) ? r1 : u1) * ((c & 1) ? r2 : u2);
    int cc = cell + ((c & 4) ? 1024 : 0) + ((c & 2) ? 32 : 0) + (c & 1);
    int chunk = chunkbase + (cc >> 6);
    int pos = atomicAdd(&fill[chunk], 1);
    entries[binstart[chunk] + pos] =
        make_uint2(__float_as_uint(w), (unsigned)(((cc & 63) << 16) | n));
  }
}

// ============================================================
// Kernel 7: gather — one block per 64-cell chunk; accumulate in
//           LDS tile [feat][cell], write transposed + occ fused
// ============================================================
__global__ __launch_bounds__(256) void gather_kernel(const uint2* __restrict__ entries,
                                                     const int* __restrict__ binstart,
                                                     const float* __restrict__ vals,
                                                     float* __restrict__ zout,
                                                     unsigned int* __restrict__ occ) {
  const int chunk = blockIdx.x;
  const int bh = chunk >> 9;
  const int c0 = (chunk & 511) << 6;
  __shared__ float T[64][65];
  const int t = threadIdx.x;
  for (int i = t; i < 64 * 65; i += 256) ((float*)T)[i] = 0.f;
  __syncthreads();

  const int e0 = binstart[chunk], e1 = binstart[chunk + 1];
  const int w = t >> 6, f = t & 63;
  const float* vbase = vals + (size_t)bh * N_ * 64;
  for (int e = e0 + w; e < e1; e += 4) {
    uint2 ent = entries[e];
    float wt = __uint_as_float(ent.x);
    int n  = ent.y & 0xFFFF;
    int cl = ent.y >> 16;
    float v = vbase[(size_t)n * 64 + f];
    atomicAdd(&T[f][cl], wt * v);
  }
  __syncthreads();

  unsigned int cnt = 0;
  float* dst = zout + (size_t)bh * 64 * NC_ + c0;
#pragma unroll
  for (int i = 0; i < 16; ++i) {
    int idx = t + i * 256;
    int ff = idx >> 6, cl = idx & 63;
    float v = T[ff][cl];
    cnt += (fabsf(v) > 1e-9f) ? 1u : 0u;
    dst[(size_t)ff * NC_ + cl] = v;
  }
#pragma unroll
  for (int off = 32; off; off >>= 1) cnt += __shfl_down(cnt, off);
  __shared__ unsigned int wc[4];
  if ((t & 63) == 0) wc[t >> 6] = cnt;
  __syncthreads();
  if (t == 0) atomicAdd(occ, wc[0] + wc[1] + wc[2] + wc[3]);
}

// ---- fallback path (small ws): direct final-layout splat ----
__global__ __launch_bounds__(256) void splat_final_kernel(const float* __restrict__ KV,
                                                          const float* __restrict__ orig,
                                                          const float* __restrict__ proj,
                                                          const float* __restrict__ scale,
                                                          const float* __restrict__ shift,
                                                          float* __restrict__ Z,
                                                          float* __restrict__ kacc) {
  const int bh = blockIdx.x >> 7;
  const int n0 = (blockIdx.x & 127) << 6;
  const int b = bh >> 3, h = bh & 7;
  __shared__ float vals[64][65];
  __shared__ int   cellS[64];
  __shared__ float rS[64][4];
  const int t = threadIdx.x;
  const float* KVb = KV + (size_t)b * OC_ * N_;
  const int ch0 = 24 + h * 64;
#pragma unroll
  for (int i = 0; i < 16; ++i) {
    int idx = t + i * 256;
    int f = idx >> 6, p = idx & 63;
    int ch = ch0 + f;
    vals[f][p] = fmaf(KVb[(size_t)ch * N_ + n0 + p], scale[ch], shift[ch]);
  }
  if (t < 64) {
    const int n = n0 + t;
    float pt[3];
#pragma unroll
    for (int k = 0; k < 3; ++k) {
      int ch = h * 3 + k;
      float kr = fmaf(KVb[(size_t)ch * N_ + n], scale[ch], shift[ch]);
      pt[k] = orig[((size_t)b * 3 + k) * N_ + n] + kr;
    }
    float ksum = 0.f, ksq = 0.f;
    int cell = 0;
    float rr[3];
#pragma unroll
    for (int d = 0; d < 3; ++d) {
      const float* pr = proj + (h * 3 + d) * 3;
      float key = pr[0] * pt[0] + pr[1] * pt[1] + pr[2] * pt[2];
      ksum += key; ksq += key * key;
      float lat = tanhf(key);
      float c = (lat + 1.0f) * 15.5f;
      float fl = floorf(c);
      fl = fminf(fmaxf(fl, 0.0f), 30.0f);
      rr[d] = c - fl;
      cell += (int)fl * ((d == 0) ? 1024 : (d == 1) ? 32 : 1);
    }
    cellS[t] = cell;
    rS[t][0] = rr[0]; rS[t][1] = rr[1]; rS[t][2] = rr[2];
#pragma unroll
    for (int off = 32; off; off >>= 1) {
      ksum += __shfl_down(ksum, off);
      ksq  += __shfl_down(ksq, off);
    }
    if (t == 0) { atomicAdd(&kacc[0], ksum); atomicAdd(&kacc[1], ksq); }
  }
  __syncthreads();
  const int w = t >> 6, l = t & 63;
  for (int pi = 0; pi < 16; ++pi) {
    int p = w * 16 + pi;
    int cell = cellS[p];
    float r0 = rS[p][0], r1 = rS[p][1], r2 = rS[p][2];
    float u0 = 1.f - r0, u1 = 1.f - r1, u2 = 1.f - r2;
    float v = vals[l][p];
#pragma unroll
    for (int c = 0; c < 8; ++c) {
      float wt = ((c & 4) ? r0 : u0) * ((c & 2) ? r1 : u1) * ((c & 1) ? r2 : u2);
      int cc = cell + ((c & 4) ? 1024 : 0) + ((c & 2) ? 32 : 0) + (c & 1);
      atomicAdd(Z + (size_t)(bh * 64 + l) * NC_ + cc, v * wt);
    }
  }
}

__global__ __launch_bounds__(256) void count_kernel(const float* __restrict__ Z,
                                                    unsigned int* __restrict__ occ) {
  unsigned int cnt = 0;
  for (long long i = (long long)blockIdx.x * blockDim.x + threadIdx.x; i < ZTOT_;
       i += (long long)gridDim.x * blockDim.x)
    cnt += (fabsf(Z[i]) > 1e-9f) ? 1u : 0u;
#pragma unroll
  for (int off = 32; off; off >>= 1) cnt += __shfl_down(cnt, off);
  __shared__ unsigned int wc[4];
  const int t = threadIdx.x;
  if ((t & 63) == 0) wc[t >> 6] = cnt;
  __syncthreads();
  if (t == 0) atomicAdd(occ, wc[0] + wc[1] + wc[2] + wc[3]);
}

__global__ void finalize_kernel(const unsigned int* __restrict__ occ,
                                const float* __restrict__ kacc,
                                float* __restrict__ tail) {
  float mean = kacc[0] / NKEYS_;
  tail[0] = (float)(*occ) * (1.0f / 2048.0f);
  tail[1] = mean;
  tail[2] = kacc[1] / NKEYS_ - mean * mean;
}

// ============================================================
extern "C" void kernel_launch(void* const* d_in, const int* in_sizes, int n_in,
                              void* d_out, int out_size, void* d_ws, size_t ws_size,
                              hipStream_t stream) {
  const float* X    = (const float*)d_in[0];
  const float* orig = (const float*)d_in[1];
  const float* W    = (const float*)d_in[2];
  const float* kg   = (const float*)d_in[3];
  const float* kb   = (const float*)d_in[4];
  const float* vg   = (const float*)d_in[5];
  const float* vb   = (const float*)d_in[6];
  const float* proj = (const float*)d_in[7];
  float* out = (float*)d_out;

  char* wsb = (char*)d_ws;
  float* scale = (float*)wsb;              // [536]
  float* shift = scale + 536;              // [536]
  float* kacc  = scale + 1072;             // [2]
  unsigned int* occ = (unsigned int*)(scale + 1074);

  const size_t need = (size_t)100 << 20;   // 96 MB layout + slack
  if (ws_size >= need) {
    int*    hist    = (int*)(wsb + 8192);            // (16384+1) ints
    int*    fill    = (int*)(wsb + 131072);          // 64 KB
    float4* cellr   = (float4*)(wsb + ((size_t)1 << 20));   // 4 MB
    uint2*  entries = (uint2*)(wsb + ((size_t)8 << 20));    // 16 MB
    float*  vals    = (float*)(wsb + ((size_t)32 << 20));   // 64 MB
    float*  kv      = out;   // z region reused; fully consumed before gather writes

    hipMemsetAsync(kacc, 0, 12, stream);                    // kacc + occ
    hipMemsetAsync(hist, 0, (NCHUNK_ + 1) * 4, stream);
    hipMemsetAsync(fill, 0, NCHUNK_ * 4, stream);

    gemm_kernel<<<dim3(N_ / 256, 9, B_), 256, 0, stream>>>(W, X, kv);
    bn_kernel<<<OC_, 256, 0, stream>>>(kv, kg, kb, vg, vb, scale, shift);
    valst_kernel<<<32 * 128, 256, 0, stream>>>(kv, scale, shift, vals);
    passk_kernel<<<NPTS_ / 256, 256, 0, stream>>>(kv, orig, proj, scale, shift,
                                                  cellr, hist, kacc);
    scan_kernel<<<1, 256, 0, stream>>>(hist);
    scatter_kernel<<<NPTS_ / 256, 256, 0, stream>>>(cellr, hist, fill, entries);
    gather_kernel<<<NCHUNK_, 256, 0, stream>>>(entries, hist, vals, out, occ);
    finalize_kernel<<<1, 1, 0, stream>>>(occ, kacc, out + ZTOT_);
  } else {
    // fallback: kv in ws, splat straight into d_out final layout
    float* kv = (float*)(wsb + 8192);
    hipMemsetAsync(kacc, 0, 12, stream);
    hipMemsetAsync(out, 0, (size_t)ZTOT_ * 4, stream);
    gemm_kernel<<<dim3(N_ / 256, 9, B_), 256, 0, stream>>>(W, X, kv);
    bn_kernel<<<OC_, 256, 0, stream>>>(kv, kg, kb, vg, vb, scale, shift);
    splat_final_kernel<<<B_ * HEADS_ * (N_ / 64), 256, 0, stream>>>(
        kv, orig, proj, scale, shift, out, kacc);
    count_kernel<<<2048, 256, 0, stream>>>(out, occ);
    finalize_kernel<<<1, 1, 0, stream>>>(occ, kacc, out + ZTOT_);
  }
}

// Round 3
// 1085.750 us; speedup vs baseline: 1.8705x; 1.8705x over previous
//
#include <hip/hip_runtime.h>
#include <hip/hip_bf16.h>

// ---- problem constants ----
#define B_     4
#define N_     8192
#define MD_    512
#define OC_    536        // HEADS*(FEAT+3)
#define HEADS_ 8
#define FEAT_  64
#define NC_    32768      // 32^3 cells
#define ZTOT_  67108864ll // B*HEADS*FEAT*NC
#define NPTS_  262144     // B*HEADS*N
#define NKEYS_ 786432.0f  // B*HEADS*3*N

// ============================================================
// Kernel 1: GEMM  kv[b][o][n] = sum_m W[o][m] * X[b][m][n]
// + fused per-channel partial sums for BN stats (atomic f32)
// ============================================================
__global__ __launch_bounds__(256) void gemm_kernel(const float* __restrict__ W,
                                                   const float* __restrict__ X,
                                                   float* __restrict__ KV,
                                                   float* __restrict__ ssum,
                                                   float* __restrict__ s2sum) {
  const int n0 = blockIdx.x * 256;
  const int m0 = blockIdx.y * 64;
  const int b  = blockIdx.z;
  __shared__ float Wt[32][68];    // Wt[k][m]
  __shared__ float In[32][260];   // In[k][n]
  const int t  = threadIdx.x;
  const int tx = t & 31;
  const int ty = t >> 5;
  float acc[8][8];
#pragma unroll
  for (int r = 0; r < 8; ++r)
#pragma unroll
    for (int c = 0; c < 8; ++c) acc[r][c] = 0.f;

  const float* Xb = X + (size_t)b * MD_ * N_;
  for (int k0 = 0; k0 < MD_; k0 += 32) {
#pragma unroll
    for (int i = 0; i < 8; ++i) {
      int idx = t + i * 256;
      int m = idx >> 5, k = idx & 31;
      int mm = m0 + m;
      Wt[k][m] = (mm < OC_) ? W[(size_t)mm * MD_ + (k0 + k)] : 0.f;
    }
#pragma unroll
    for (int i = 0; i < 8; ++i) {
      int slot = t + i * 256;
      int k = slot >> 6, n4 = slot & 63;
      float4 v = *(const float4*)(Xb + (size_t)(k0 + k) * N_ + n0 + n4 * 4);
      *(float4*)&In[k][n4 * 4] = v;
    }
    __syncthreads();
#pragma unroll
    for (int k = 0; k < 32; ++k) {
      float a[8], bb[8];
      *(float4*)&a[0]  = *(const float4*)&Wt[k][ty * 8];
      *(float4*)&a[4]  = *(const float4*)&Wt[k][ty * 8 + 4];
      *(float4*)&bb[0] = *(const float4*)&In[k][tx * 4];
      *(float4*)&bb[4] = *(const float4*)&In[k][128 + tx * 4];
#pragma unroll
      for (int r = 0; r < 8; ++r)
#pragma unroll
        for (int c = 0; c < 8; ++c)
          acc[r][c] = fmaf(a[r], bb[c], acc[r][c]);
    }
    __syncthreads();
  }
#pragma unroll
  for (int r = 0; r < 8; ++r) {
    int mm = m0 + ty * 8 + r;
    float s = 0.f, s2 = 0.f;
#pragma unroll
    for (int c = 0; c < 8; ++c) { float v = acc[r][c]; s += v; s2 = fmaf(v, v, s2); }
#pragma unroll
    for (int off = 16; off; off >>= 1) {
      s  += __shfl_down(s, off, 32);
      s2 += __shfl_down(s2, off, 32);
    }
    if (mm < OC_) {
      float* dst = KV + ((size_t)b * OC_ + mm) * N_ + n0;
      *(float4*)(dst + tx * 4)       = *(float4*)&acc[r][0];
      *(float4*)(dst + 128 + tx * 4) = *(float4*)&acc[r][4];
      if (tx == 0) { atomicAdd(&ssum[mm], s); atomicAdd(&s2sum[mm], s2); }
    }
  }
}

// ============================================================
// Kernel 2: finalize BN -> scale/shift per channel
// ============================================================
__global__ __launch_bounds__(256) void bnfin_kernel(const float* __restrict__ ssum,
                                                    const float* __restrict__ s2sum,
                                                    const float* __restrict__ kg,
                                                    const float* __restrict__ kb,
                                                    const float* __restrict__ vg,
                                                    const float* __restrict__ vb,
                                                    float* __restrict__ scale,
                                                    float* __restrict__ shift) {
  const int o = blockIdx.x * 256 + threadIdx.x;
  if (o >= OC_) return;
  const float inv = 1.0f / (B_ * N_);
  float mu  = ssum[o] * inv;
  float var = s2sum[o] * inv - mu * mu;
  float g, be;
  if (o < 24) { g = kg[o]; be = kb[o]; }
  else        { g = vg[o - 24]; be = vb[o - 24]; }
  float sc = g * rsqrtf(var + 1e-5f);
  scale[o] = sc;
  shift[o] = be - mu * sc;
}

// ============================================================
// Kernel 3: per-point keys -> cell index + 8 corner weights
//           + keys mean/var partials
// ============================================================
__global__ __launch_bounds__(256) void passk_kernel(const float* __restrict__ KV,
                                                    const float* __restrict__ orig,
                                                    const float* __restrict__ proj,
                                                    const float* __restrict__ scale,
                                                    const float* __restrict__ shift,
                                                    int* __restrict__ cellidx,
                                                    float4* __restrict__ w0,
                                                    float4* __restrict__ w1,
                                                    float* __restrict__ kacc) {
  const int p = blockIdx.x * 256 + threadIdx.x;
  const int bh = p >> 13, n = p & (N_ - 1);
  const int b = bh >> 3, h = bh & 7;
  const float* KVb = KV + (size_t)b * OC_ * N_;
  float pt[3];
#pragma unroll
  for (int k = 0; k < 3; ++k) {
    int ch = h * 3 + k;
    float kr = fmaf(KVb[(size_t)ch * N_ + n], scale[ch], shift[ch]);
    pt[k] = orig[((size_t)b * 3 + k) * N_ + n] + kr;
  }
  float ksum = 0.f, ksq = 0.f;
  int cell = 0;
  float rr[3];
#pragma unroll
  for (int d = 0; d < 3; ++d) {
    const float* pr = proj + (h * 3 + d) * 3;
    float key = pr[0] * pt[0] + pr[1] * pt[1] + pr[2] * pt[2];
    ksum += key; ksq += key * key;
    float lat = tanhf(key);
    float c = (lat + 1.0f) * 15.5f;
    float fl = floorf(c);
    fl = fminf(fmaxf(fl, 0.0f), 30.0f);
    rr[d] = c - fl;
    cell += (int)fl * ((d == 0) ? 1024 : (d == 1) ? 32 : 1);
  }
  const float r0 = rr[0], r1 = rr[1], r2 = rr[2];
  const float u0 = 1.f - r0, u1 = 1.f - r1, u2 = 1.f - r2;
  cellidx[p] = cell;
  // corner c: bit2 -> d0(+1024), bit1 -> d1(+32), bit0 -> d2(+1)
  w0[p] = make_float4(u0 * u1 * u2, u0 * u1 * r2, u0 * r1 * u2, u0 * r1 * r2);
  w1[p] = make_float4(r0 * u1 * u2, r0 * u1 * r2, r0 * r1 * u2, r0 * r1 * r2);
#pragma unroll
  for (int off = 32; off; off >>= 1) {
    ksum += __shfl_down(ksum, off);
    ksq  += __shfl_down(ksq, off);
  }
  if ((threadIdx.x & 63) == 0) {
    atomicAdd(&kacc[0], ksum);
    atomicAdd(&kacc[1], ksq);
  }
}

// ============================================================
// Kernel 4: dense accumulate — block = (bh, feat, grid-half)
// 64KB LDS tile of 16384 cells; stream all 8192 points of the
// (b,h); LDS atomics only; coalesced non-atomic z write + occ.
// Perfectly load-balanced regardless of cell skew.
// ============================================================
__global__ __launch_bounds__(256) void accum_kernel(const float* __restrict__ KV,
                                                    const float* __restrict__ scale,
                                                    const float* __restrict__ shift,
                                                    const int* __restrict__ cellidx,
                                                    const float4* __restrict__ w0,
                                                    const float4* __restrict__ w1,
                                                    float* __restrict__ zout,
                                                    unsigned int* __restrict__ occ) {
  const int blk  = blockIdx.x;
  const int half = blk & 1;
  const int f    = (blk >> 1) & 63;
  const int bh   = blk >> 7;
  const int b = bh >> 3, h = bh & 7;
  __shared__ float tile[16384];   // 64 KB
  const int t = threadIdx.x;
#pragma unroll
  for (int i = 0; i < 16; ++i)
    ((float4*)tile)[t + i * 256] = make_float4(0.f, 0.f, 0.f, 0.f);
  __syncthreads();

  const int ch = 24 + h * 64 + f;
  const float sc = scale[ch], sh = shift[ch];
  const float* kvrow = KV + ((size_t)b * OC_ + ch) * N_;
  const int pbase = bh * N_;
  const int lo = half << 14;

  for (int n = t; n < N_; n += 256) {
    int   c0 = cellidx[pbase + n] - lo;
    float4 wa = w0[pbase + n];
    float4 wb = w1[pbase + n];
    float v = fmaf(kvrow[n], sc, sh);
#define CORNER(W, OFF)                                             \
    { int cc = c0 + (OFF);                                         \
      if ((unsigned)cc < 16384u) atomicAdd(&tile[cc], (W) * v); }
    CORNER(wa.x, 0)    CORNER(wa.y, 1)    CORNER(wa.z, 32)   CORNER(wa.w, 33)
    CORNER(wb.x, 1024) CORNER(wb.y, 1025) CORNER(wb.z, 1056) CORNER(wb.w, 1057)
#undef CORNER
  }
  __syncthreads();

  unsigned int cnt = 0;
  float* dst = zout + ((size_t)(bh * 64 + f)) * NC_ + lo;
#pragma unroll
  for (int i = 0; i < 16; ++i) {
    float4 v = ((const float4*)tile)[t + i * 256];
    cnt += (fabsf(v.x) > 1e-9f) ? 1u : 0u;
    cnt += (fabsf(v.y) > 1e-9f) ? 1u : 0u;
    cnt += (fabsf(v.z) > 1e-9f) ? 1u : 0u;
    cnt += (fabsf(v.w) > 1e-9f) ? 1u : 0u;
    ((float4*)dst)[t + i * 256] = v;
  }
#pragma unroll
  for (int off = 32; off; off >>= 1) cnt += __shfl_down(cnt, off);
  __shared__ unsigned int wc[4];
  if ((t & 63) == 0) wc[t >> 6] = cnt;
  __syncthreads();
  if (t == 0) atomicAdd(occ, wc[0] + wc[1] + wc[2] + wc[3]);
}

// ---- fallback path (small ws): direct final-layout splat ----
__global__ __launch_bounds__(256) void splat_final_kernel(const float* __restrict__ KV,
                                                          const float* __restrict__ orig,
                                                          const float* __restrict__ proj,
                                                          const float* __restrict__ scale,
                                                          const float* __restrict__ shift,
                                                          float* __restrict__ Z,
                                                          float* __restrict__ kacc) {
  const int bh = blockIdx.x >> 7;
  const int n0 = (blockIdx.x & 127) << 6;
  const int b = bh >> 3, h = bh & 7;
  __shared__ float vals[64][65];
  __shared__ int   cellS[64];
  __shared__ float rS[64][4];
  const int t = threadIdx.x;
  const float* KVb = KV + (size_t)b * OC_ * N_;
  const int ch0 = 24 + h * 64;
#pragma unroll
  for (int i = 0; i < 16; ++i) {
    int idx = t + i * 256;
    int f = idx >> 6, p = idx & 63;
    int ch = ch0 + f;
    vals[f][p] = fmaf(KVb[(size_t)ch * N_ + n0 + p], scale[ch], shift[ch]);
  }
  if (t < 64) {
    const int n = n0 + t;
    float pt[3];
#pragma unroll
    for (int k = 0; k < 3; ++k) {
      int ch = h * 3 + k;
      float kr = fmaf(KVb[(size_t)ch * N_ + n], scale[ch], shift[ch]);
      pt[k] = orig[((size_t)b * 3 + k) * N_ + n] + kr;
    }
    float ksum = 0.f, ksq = 0.f;
    int cell = 0;
    float rr[3];
#pragma unroll
    for (int d = 0; d < 3; ++d) {
      const float* pr = proj + (h * 3 + d) * 3;
      float key = pr[0] * pt[0] + pr[1] * pt[1] + pr[2] * pt[2];
      ksum += key; ksq += key * key;
      float lat = tanhf(key);
      float c = (lat + 1.0f) * 15.5f;
      float fl = floorf(c);
      fl = fminf(fmaxf(fl, 0.0f), 30.0f);
      rr[d] = c - fl;
      cell += (int)fl * ((d == 0) ? 1024 : (d == 1) ? 32 : 1);
    }
    cellS[t] = cell;
    rS[t][0] = rr[0]; rS[t][1] = rr[1]; rS[t][2] = rr[2];
#pragma unroll
    for (int off = 32; off; off >>= 1) {
      ksum += __shfl_down(ksum, off);
      ksq  += __shfl_down(ksq, off);
    }
    if (t == 0) { atomicAdd(&kacc[0], ksum); atomicAdd(&kacc[1], ksq); }
  }
  __syncthreads();
  const int w = t >> 6, l = t & 63;
  for (int pi = 0; pi < 16; ++pi) {
    int p = w * 16 + pi;
    int cell = cellS[p];
    float r0 = rS[p][0], r1 = rS[p][1], r2 = rS[p][2];
    float u0 = 1.f - r0, u1 = 1.f - r1, u2 = 1.f - r2;
    float v = vals[l][p];
#pragma unroll
    for (int c = 0; c < 8; ++c) {
      float wt = ((c & 4) ? r0 : u0) * ((c & 2) ? r1 : u1) * ((c & 1) ? r2 : u2);
      int cc = cell + ((c & 4) ? 1024 : 0) + ((c & 2) ? 32 : 0) + (c & 1);
      atomicAdd(Z + (size_t)(bh * 64 + l) * NC_ + cc, v * wt);
    }
  }
}

__global__ __launch_bounds__(256) void count_kernel(const float* __restrict__ Z,
                                                    unsigned int* __restrict__ occ) {
  unsigned int cnt = 0;
  for (long long i = (long long)blockIdx.x * blockDim.x + threadIdx.x; i < ZTOT_;
       i += (long long)gridDim.x * blockDim.x)
    cnt += (fabsf(Z[i]) > 1e-9f) ? 1u : 0u;
#pragma unroll
  for (int off = 32; off; off >>= 1) cnt += __shfl_down(cnt, off);
  __shared__ unsigned int wc[4];
  const int t = threadIdx.x;
  if ((t & 63) == 0) wc[t >> 6] = cnt;
  __syncthreads();
  if (t == 0) atomicAdd(occ, wc[0] + wc[1] + wc[2] + wc[3]);
}

__global__ void finalize_kernel(const unsigned int* __restrict__ occ,
                                const float* __restrict__ kacc,
                                float* __restrict__ tail) {
  float mean = kacc[0] / NKEYS_;
  tail[0] = (float)(*occ) * (1.0f / 2048.0f);
  tail[1] = mean;
  tail[2] = kacc[1] / NKEYS_ - mean * mean;
}

// ============================================================
extern "C" void kernel_launch(void* const* d_in, const int* in_sizes, int n_in,
                              void* d_out, int out_size, void* d_ws, size_t ws_size,
                              hipStream_t stream) {
  const float* X    = (const float*)d_in[0];
  const float* orig = (const float*)d_in[1];
  const float* W    = (const float*)d_in[2];
  const float* kg   = (const float*)d_in[3];
  const float* kb   = (const float*)d_in[4];
  const float* vg   = (const float*)d_in[5];
  const float* vb   = (const float*)d_in[6];
  const float* proj = (const float*)d_in[7];
  float* out = (float*)d_out;

  // ws stats page (16 KB)
  float* P = (float*)d_ws;
  float* ssum  = P;                         // [536]
  float* s2sum = P + 544;                   // [536]
  float* kacc  = P + 1088;                  // [2]
  unsigned int* occ = (unsigned int*)(P + 1090);
  float* scale = P + 1152;                  // [536]
  float* shift = P + 1696;                  // [536]
  char* wsb = (char*)d_ws;

  const size_t need = (size_t)82 << 20;
  if (ws_size >= need) {
    int*    cellidx = (int*)(wsb + 16384);                  // 1 MB
    float4* w0      = (float4*)(wsb + ((size_t)2 << 20));   // 4 MB
    float4* w1      = (float4*)(wsb + ((size_t)6 << 20));   // 4 MB
    float*  kv      = (float*)(wsb + ((size_t)10 << 20));   // 70.3 MB

    // zero ssum/s2sum/kacc/occ (through P+1091)
    hipMemsetAsync(P, 0, 4368, stream);

    gemm_kernel<<<dim3(N_ / 256, 9, B_), 256, 0, stream>>>(W, X, kv, ssum, s2sum);
    bnfin_kernel<<<3, 256, 0, stream>>>(ssum, s2sum, kg, kb, vg, vb, scale, shift);
    passk_kernel<<<NPTS_ / 256, 256, 0, stream>>>(kv, orig, proj, scale, shift,
                                                  cellidx, w0, w1, kacc);
    accum_kernel<<<4096, 256, 0, stream>>>(kv, scale, shift, cellidx, w0, w1, out, occ);
    finalize_kernel<<<1, 1, 0, stream>>>(occ, kacc, out + ZTOT_);
  } else {
    // fallback: kv in ws, splat straight into d_out final layout
    float* kv = (float*)(wsb + 16384);
    hipMemsetAsync(P, 0, 4368, stream);
    hipMemsetAsync(out, 0, (size_t)ZTOT_ * 4, stream);
    gemm_kernel<<<dim3(N_ / 256, 9, B_), 256, 0, stream>>>(W, X, kv, ssum, s2sum);
    bnfin_kernel<<<3, 256, 0, stream>>>(ssum, s2sum, kg, kb, vg, vb, scale, shift);
    splat_final_kernel<<<B_ * HEADS_ * (N_ / 64), 256, 0, stream>>>(
        kv, orig, proj, scale, shift, out, kacc);
    count_kernel<<<2048, 256, 0, stream>>>(out, occ);
    finalize_kernel<<<1, 1, 0, stream>>>(occ, kacc, out + ZTOT_);
  }
}